// Round 7
// baseline (168.516 us; speedup 1.0000x reference)
//
#include <hip/hip_runtime.h>
#include <hip/hip_fp16.h>

// GCN 2-layer, pull-based CSR gather, fp16 dense intermediates.
// R20 (after R19 cooperative crash - VGPR-occupancy made 587 blocks non-
// co-resident; abandoned): non-cooperative, two changes vs R18:
//  (a) scale_k removed: gather1 goes back to per-edge dinv[src] weighting
//      (1 extra shfl/edge; dinv is 200KB -> L2-resident). -51 MB, -1 launch.
//  (b) gather1 split into TWO PASS KERNELS over 64-dim panels of hs1
//      (stored as two [N][64] fp16 panels; 128B rows = one cache line).
//      Kernel boundary = hard device-wide barrier -> per-pass working set
//      is one 6.4MB panel (vs 12.8MB), raising per-XCD L2 hit rate - the
//      guarantee R18's loose source-tiled ordering could not provide.
//      Pass A writes relu'd g1 dims 0-63 (g1_lo); pass B computes dims
//      64-127, stages g1_lo, runs the M=16 MFMA (gemm2) -> hs2*dinv.
// k1 (gemm1 ∪ binA), binB (2048-key src-tiled sort), gather2 unchanged.
// N <= 65536.

typedef _Float16 half_t;
typedef _Float16 half2_t __attribute__((ext_vector_type(2)));
typedef _Float16 f16x4 __attribute__((ext_vector_type(4)));
typedef _Float16 f16x8 __attribute__((ext_vector_type(8)));
typedef float f32x4 __attribute__((ext_vector_type(4)));

#define BKT_CAP 8192   // per-bucket ebuf capacity (expected load 4096, sigma 64)

// inclusive block scan over 256 threads (4 waves); caller provides 4-int LDS
__device__ __forceinline__ int incl_scan256(int v, volatile int* wsum) {
    int t = threadIdx.x, lane = t & 63, w = t >> 6;
#pragma unroll
    for (int off = 1; off < 64; off <<= 1) {
        int u = __shfl_up(v, off);
        if (lane >= off) v += u;
    }
    if (lane == 63) wsum[w] = v;
    __syncthreads();
    int add = 0;
#pragma unroll
    for (int i = 0; i < 3; ++i)
        if (i < w) add += wsum[i];
    return v + add;
}

// ---------------- gemm1: 128x128 tile via f16 MFMA, panel output ------------
// MFMA 16x16x32 layouts (gfx950, HW-verified):
//   A-frag: lane holds A[m=lane&15][k=(lane>>4)*8+j]
//   B-frag: lane holds B[k=(lane>>4)*8+j][n=lane&15]
//   C/D   : col=lane&15, row=(lane>>4)*4+reg
// Output: two [M][64] fp16 panels (panel p = dims 64p..64p+63), unscaled.

__device__ __forceinline__ void gemm1_mfma(const float* __restrict__ x,
                                           const float* __restrict__ W,
                                           half_t* __restrict__ C, int M, int r0) {
    __shared__ _Float16 Wt[128][136];          // [n][k], rows 272B (b128-aligned)
    __shared__ _Float16 Xs[128][40];           // [m][k-chunk], rows 80B
    const int t = threadIdx.x;
    const size_t PN = (size_t)M * 64;          // panel stride (halfs)

    // stage W^T fp16: coalesced reads along n, b64 writes along k
    {
        const int n = t & 127;
#pragma unroll
        for (int kb = (t >> 7) * 4; kb < 128; kb += 8) {
            f16x4 hv;
            hv[0] = (_Float16)W[(size_t)(kb + 0) * 128 + n];
            hv[1] = (_Float16)W[(size_t)(kb + 1) * 128 + n];
            hv[2] = (_Float16)W[(size_t)(kb + 2) * 128 + n];
            hv[3] = (_Float16)W[(size_t)(kb + 3) * 128 + n];
            *(f16x4*)&Wt[n][kb] = hv;
        }
    }

    const int w = t >> 6, lane = t & 63;
    const int m = lane & 15, q = lane >> 4;

    // Xs staging coords: 16 floats (one row-half-chunk) per thread per kc
    const int sr = t >> 1;               // 0..127 tile row
    const int sk = (t & 1) * 16;         // 0 or 16 within 32-k chunk
    const int srow = (r0 + sr < M) ? (r0 + sr) : (M - 1);

    f32x4 acc[2][8];
#pragma unroll
    for (int rt = 0; rt < 2; ++rt)
#pragma unroll
        for (int ct = 0; ct < 8; ++ct)
#pragma unroll
            for (int r = 0; r < 4; ++r) acc[rt][ct][r] = 0.f;

#pragma unroll
    for (int kc = 0; kc < 4; ++kc) {
        // coalesced global loads issued before the barrier (overlap prev MFMAs)
        const float* xp = &x[(size_t)srow * 128 + kc * 32 + sk];
        float4 v0 = *(const float4*)xp;
        float4 v1 = *(const float4*)(xp + 4);
        float4 v2 = *(const float4*)(xp + 8);
        float4 v3 = *(const float4*)(xp + 12);
        __syncthreads();                 // prev iter's Xs reads done (&& Wt staged)
        f16x8 s0, s1;
        s0[0] = (_Float16)v0.x; s0[1] = (_Float16)v0.y;
        s0[2] = (_Float16)v0.z; s0[3] = (_Float16)v0.w;
        s0[4] = (_Float16)v1.x; s0[5] = (_Float16)v1.y;
        s0[6] = (_Float16)v1.z; s0[7] = (_Float16)v1.w;
        s1[0] = (_Float16)v2.x; s1[1] = (_Float16)v2.y;
        s1[2] = (_Float16)v2.z; s1[3] = (_Float16)v2.w;
        s1[4] = (_Float16)v3.x; s1[5] = (_Float16)v3.y;
        s1[6] = (_Float16)v3.z; s1[7] = (_Float16)v3.w;
        *(f16x8*)&Xs[sr][sk] = s0;
        *(f16x8*)&Xs[sr][sk + 8] = s1;
        __syncthreads();

        const int k0 = q * 8;
        f16x8 a0 = *(const f16x8*)&Xs[(w * 2 + 0) * 16 + m][k0];
        f16x8 a1 = *(const f16x8*)&Xs[(w * 2 + 1) * 16 + m][k0];
        const int kw = kc * 32 + k0;
#pragma unroll
        for (int ct = 0; ct < 8; ++ct) {
            f16x8 b = *(const f16x8*)&Wt[ct * 16 + m][kw];
            acc[0][ct] = __builtin_amdgcn_mfma_f32_16x16x32_f16(a0, b, acc[0][ct], 0, 0, 0);
            acc[1][ct] = __builtin_amdgcn_mfma_f32_16x16x32_f16(a1, b, acc[1][ct], 0, 0, 0);
        }
    }

#pragma unroll
    for (int rt = 0; rt < 2; ++rt)
#pragma unroll
        for (int ct = 0; ct < 8; ++ct)
#pragma unroll
            for (int r = 0; r < 4; ++r) {
                int row = r0 + (w * 2 + rt) * 16 + q * 4 + r;
                if (row < M)
                    C[(size_t)(ct >> 2) * PN + (size_t)row * 64 + (ct & 3) * 16 + m] =
                        (half_t)acc[rt][ct][r];
            }
}

// ---------------- k1: gemm1 blocks, then pass-A binning blocks --------------

__launch_bounds__(256)
__global__ void gemm_binA_k(const float* __restrict__ A, const float* __restrict__ W,
                            half_t* __restrict__ C, int M, int Gg1,
                            const int* __restrict__ esrc, const int* __restrict__ edst,
                            int* __restrict__ bucket_cnt, unsigned int* __restrict__ ebuf,
                            int E) {
    int b = blockIdx.x;
    if (b < Gg1) {
        gemm1_mfma(A, W, C, M, b * 128);
        return;
    }
    __shared__ int cntA[256];
    __shared__ int curA[256];
    __shared__ int deltaA[256];
    __shared__ int wsumA[4];

    const int t = threadIdx.x;
    const int base = (b - Gg1) * 4096;
    int ls[16], ld[16];

    cntA[t] = 0;
    __syncthreads();
#pragma unroll
    for (int j = 0; j < 16; ++j) {
        int idx = base + j * 256 + t;
        if (idx < E) {
            ls[j] = esrc[idx];
            ld[j] = edst[idx];
            atomicAdd(&cntA[ld[j] >> 8], 1);
        } else {
            ls[j] = -1;
            ld[j] = 0;
        }
    }
    __syncthreads();

    int c = cntA[t];
    int incl = incl_scan256(c, wsumA);      // contains a __syncthreads
    int excl = incl - c;
    int gbase = atomicAdd(&bucket_cnt[t], c);       // offset within bucket segment
    deltaA[t] = t * BKT_CAP + gbase - excl;         // absolute = seg base + offset
    curA[t] = excl;
    __syncthreads();

#pragma unroll
    for (int j = 0; j < 16; ++j) {
        if (ls[j] >= 0) {
            int bkt = ld[j] >> 8;
            int p = atomicAdd(&curA[bkt], 1);
            ebuf[deltaA[bkt] + p] = ((unsigned int)ls[j] << 8) | ((unsigned int)ld[j] & 255u);
        }
    }
}

// ---------------- k2 (pass B): per-bucket counting sort -> rs/dinv/ssrc -----
// Sort key = ((dst&255)<<3) | (src>>13): per-node adjacency grouped by
// 8192-node source tile (R18 ordering, kept).

__launch_bounds__(256)
__global__ void binB_k(const int* __restrict__ bucket_cnt,
                       const unsigned int* __restrict__ ebuf,
                       unsigned short* __restrict__ ssrc,
                       int* __restrict__ rs, float* __restrict__ dinv,
                       int N, int NB) {
    __shared__ int cnt[2048];                  // per (dstlow, tile) counters
    __shared__ int pre[256];
    __shared__ int wsum1[4];
    __shared__ int wsum2[4];

    const int t = threadIdx.x;
    const int b = blockIdx.x;

    int v = (t < NB) ? bucket_cnt[t] : 0;
    int inclb = incl_scan256(v, wsum1);
    pre[t] = inclb;
    __syncthreads();
    const int gb = (b > 0) ? pre[b - 1] : 0;
    const int sz = pre[b] - gb;
    const unsigned int* seg = ebuf + (size_t)b * BKT_CAP;

#pragma unroll
    for (int i = 0; i < 8; ++i) cnt[t + i * 256] = 0;
    __syncthreads();
    for (int i = t; i < sz; i += 256) {
        unsigned int pk = seg[i];
        int key = ((pk & 255u) << 3) | ((pk >> 8) >> 13);   // (dstlow, srctile)
        atomicAdd(&cnt[key], 1);
    }
    __syncthreads();

    // thread t owns keys 8t..8t+7 (= node dstlow t, all 8 tiles)
    int c8[8];
    int s = 0;
#pragma unroll
    for (int j = 0; j < 8; ++j) { c8[j] = cnt[t * 8 + j]; s += c8[j]; }
    int incl = incl_scan256(s, wsum2);         // contains a __syncthreads
    int excl = incl - s;
    int node = b * 256 + t;
    if (node < N) {
        rs[node] = gb + excl;
        dinv[node] = rsqrtf(1.0f + (float)s);
    }
    int run = excl;
#pragma unroll
    for (int j = 0; j < 8; ++j) { int cv = c8[j]; cnt[t * 8 + j] = run; run += cv; }
    __syncthreads();

    for (int i = t; i < sz; i += 256) {
        unsigned int pk = seg[i];
        int key = ((pk & 255u) << 3) | ((pk >> 8) >> 13);
        int p = atomicAdd(&cnt[key], 1);
        ssrc[gb + p] = (unsigned short)(pk >> 8);
    }
}

// ---------------- g1a: gather1 pass 0 (dims 0-63), weighted, -> g1_lo -------
// Quarter-wave per node (16 lanes x f16x4 = 64 dims; 128B row = 1 line).
// acc = h[node]*dv + sum_s h_lo[s]*dinv[s]; out = relu(acc*dv + b1[0:64]).

__launch_bounds__(256)
__global__ void g1a_k(const half_t* __restrict__ hs_lo,
                      const unsigned short* __restrict__ ssrc,
                      const int* __restrict__ rs,
                      const float* __restrict__ dinv,
                      const float* __restrict__ b1,
                      half_t* __restrict__ glo, int N, int E) {
    const int t = threadIdx.x;
    const int lane = t & 63;
    const int qd = lane >> 4, l4 = lane & 15;
    const int w = t >> 6;
    const int sl = qd * 16;

    int node = blockIdx.x * 16 + w * 4 + qd;
    int vnode = (node < N) ? node : (N - 1);
    int start = rs[vnode];
    int end = (vnode + 1 < N) ? rs[vnode + 1] : E;
    float dv = dinv[vnode];

    const half_t* hp = hs_lo + 4 * l4;         // dims 4*l4 .. 4*l4+3
    f16x4 sv = *(const f16x4*)&hp[(size_t)vnode * 64];
    float acc[4];
#pragma unroll
    for (int j = 0; j < 4; ++j) acc[j] = (float)sv[j] * dv;   // self (dv^2 w/ epilogue)

    for (int base = start; base < end; base += 16) {
        int n = end - base;
        if (n > 16) n = 16;
        int gi = (base + l4 < end) ? (base + l4) : base;
        int idx = (int)ssrc[gi];
        float dw = dinv[idx];
        int e = 0;
        for (; e + 4 <= n; e += 4) {
            int s0 = __shfl(idx, sl + e + 0);
            int s1 = __shfl(idx, sl + e + 1);
            int s2 = __shfl(idx, sl + e + 2);
            int s3 = __shfl(idx, sl + e + 3);
            float w0 = __shfl(dw, sl + e + 0);
            float w1 = __shfl(dw, sl + e + 1);
            float w2 = __shfl(dw, sl + e + 2);
            float w3 = __shfl(dw, sl + e + 3);
            f16x4 x0 = *(const f16x4*)&hp[(size_t)s0 * 64];
            f16x4 x1 = *(const f16x4*)&hp[(size_t)s1 * 64];
            f16x4 x2 = *(const f16x4*)&hp[(size_t)s2 * 64];
            f16x4 x3 = *(const f16x4*)&hp[(size_t)s3 * 64];
#pragma unroll
            for (int j = 0; j < 4; ++j) acc[j] = fmaf((float)x0[j], w0, acc[j]);
#pragma unroll
            for (int j = 0; j < 4; ++j) acc[j] = fmaf((float)x1[j], w1, acc[j]);
#pragma unroll
            for (int j = 0; j < 4; ++j) acc[j] = fmaf((float)x2[j], w2, acc[j]);
#pragma unroll
            for (int j = 0; j < 4; ++j) acc[j] = fmaf((float)x3[j], w3, acc[j]);
        }
        for (; e < n; ++e) {
            int s0 = __shfl(idx, sl + e);
            float w0 = __shfl(dw, sl + e);
            f16x4 x0 = *(const f16x4*)&hp[(size_t)s0 * 64];
#pragma unroll
            for (int j = 0; j < 4; ++j) acc[j] = fmaf((float)x0[j], w0, acc[j]);
        }
    }

    if (node < N) {
        float4 bb = *(const float4*)&b1[4 * l4];
        f16x4 hv;
        hv[0] = (half_t)fmaxf(acc[0] * dv + bb.x, 0.f);
        hv[1] = (half_t)fmaxf(acc[1] * dv + bb.y, 0.f);
        hv[2] = (half_t)fmaxf(acc[2] * dv + bb.z, 0.f);
        hv[3] = (half_t)fmaxf(acc[3] * dv + bb.w, 0.f);
        *(f16x4*)&glo[(size_t)node * 64 + 4 * l4] = hv;
    }
}

// ---------------- g1b: gather1 pass 1 (dims 64-127) + gemm2 -----------------
// Same weighted gather on panel1 -> g1s[.][64:128]; stage g1_lo rows ->
// g1s[.][0:64]; then M=16 x N=64 x K=128 MFMA with W2^T; epilogue *dinv
// (pre-scales hs2 for gather2).

__launch_bounds__(256)
__global__ void g1b_k(const half_t* __restrict__ hs_hi,
                      const half_t* __restrict__ glo,
                      const unsigned short* __restrict__ ssrc,
                      const int* __restrict__ rs,
                      const float* __restrict__ dinv,
                      const float* __restrict__ b1,
                      const float* __restrict__ W2,
                      half_t* __restrict__ o, int N, int E) {
    __shared__ _Float16 Wt[64][136];           // [n][k], W2^T fp16
    __shared__ _Float16 g1s[16][136];          // full g1 rows
    const int t = threadIdx.x;

    // stage W2^T fp16: coalesced reads along n, b64 writes along k
    {
        const int n = t & 63;
#pragma unroll
        for (int kb = (t >> 6) * 4; kb < 128; kb += 16) {
            f16x4 hv;
            hv[0] = (_Float16)W2[(size_t)(kb + 0) * 64 + n];
            hv[1] = (_Float16)W2[(size_t)(kb + 1) * 64 + n];
            hv[2] = (_Float16)W2[(size_t)(kb + 2) * 64 + n];
            hv[3] = (_Float16)W2[(size_t)(kb + 3) * 64 + n];
            *(f16x4*)&Wt[n][kb] = hv;
        }
    }

    const int w = t >> 6, lane = t & 63;
    const int qd = lane >> 4, l4 = lane & 15;
    const int nb = blockIdx.x * 16;
    const int sl = qd * 16;

    // stage g1_lo rows for this block's 16 nodes (coalesced 128B per node)
    {
        int nl = t >> 4, li = t & 15;
        int gn = nb + nl;
        if (gn >= N) gn = N - 1;
        *(f16x4*)&g1s[nl][4 * li] = *(const f16x4*)&glo[(size_t)gn * 64 + 4 * li];
    }

    int node = nb + w * 4 + qd;
    int vnode = (node < N) ? node : (N - 1);
    int start = rs[vnode];
    int end = (vnode + 1 < N) ? rs[vnode + 1] : E;
    float dv = dinv[vnode];

    const half_t* hp = hs_hi + 4 * l4;         // dims 64+4*l4 ..
    f16x4 sv = *(const f16x4*)&hp[(size_t)vnode * 64];
    float acc[4];
#pragma unroll
    for (int j = 0; j < 4; ++j) acc[j] = (float)sv[j] * dv;

    for (int base = start; base < end; base += 16) {
        int n = end - base;
        if (n > 16) n = 16;
        int gi = (base + l4 < end) ? (base + l4) : base;
        int idx = (int)ssrc[gi];
        float dw = dinv[idx];
        int e = 0;
        for (; e + 4 <= n; e += 4) {
            int s0 = __shfl(idx, sl + e + 0);
            int s1 = __shfl(idx, sl + e + 1);
            int s2 = __shfl(idx, sl + e + 2);
            int s3 = __shfl(idx, sl + e + 3);
            float w0 = __shfl(dw, sl + e + 0);
            float w1 = __shfl(dw, sl + e + 1);
            float w2 = __shfl(dw, sl + e + 2);
            float w3 = __shfl(dw, sl + e + 3);
            f16x4 x0 = *(const f16x4*)&hp[(size_t)s0 * 64];
            f16x4 x1 = *(const f16x4*)&hp[(size_t)s1 * 64];
            f16x4 x2 = *(const f16x4*)&hp[(size_t)s2 * 64];
            f16x4 x3 = *(const f16x4*)&hp[(size_t)s3 * 64];
#pragma unroll
            for (int j = 0; j < 4; ++j) acc[j] = fmaf((float)x0[j], w0, acc[j]);
#pragma unroll
            for (int j = 0; j < 4; ++j) acc[j] = fmaf((float)x1[j], w1, acc[j]);
#pragma unroll
            for (int j = 0; j < 4; ++j) acc[j] = fmaf((float)x2[j], w2, acc[j]);
#pragma unroll
            for (int j = 0; j < 4; ++j) acc[j] = fmaf((float)x3[j], w3, acc[j]);
        }
        for (; e < n; ++e) {
            int s0 = __shfl(idx, sl + e);
            float w0 = __shfl(dw, sl + e);
            f16x4 x0 = *(const f16x4*)&hp[(size_t)s0 * 64];
#pragma unroll
            for (int j = 0; j < 4; ++j) acc[j] = fmaf((float)x0[j], w0, acc[j]);
        }
    }

    // epilogue: relu(acc*dv + b1[64+4*l4 ..]) -> g1s high half
    {
        float4 bb = *(const float4*)&b1[64 + 4 * l4];
        f16x4 hv;
        hv[0] = (half_t)fmaxf(acc[0] * dv + bb.x, 0.f);
        hv[1] = (half_t)fmaxf(acc[1] * dv + bb.y, 0.f);
        hv[2] = (half_t)fmaxf(acc[2] * dv + bb.z, 0.f);
        hv[3] = (half_t)fmaxf(acc[3] * dv + bb.w, 0.f);
        *(f16x4*)&g1s[w * 4 + qd][64 + 4 * l4] = hv;
    }
    __syncthreads();

    // M=16 x N=64 x K=128 MFMA; wave w owns output cols w*16..w*16+15
    const int m = lane & 15, q = lane >> 4;
    f32x4 acc2;
#pragma unroll
    for (int r = 0; r < 4; ++r) acc2[r] = 0.f;
#pragma unroll
    for (int kc = 0; kc < 4; ++kc) {
        const int k0 = kc * 32 + q * 8;
        f16x8 a = *(const f16x8*)&g1s[m][k0];
        f16x8 b = *(const f16x8*)&Wt[w * 16 + m][k0];
        acc2 = __builtin_amdgcn_mfma_f32_16x16x32_f16(a, b, acc2, 0, 0, 0);
    }
#pragma unroll
    for (int r = 0; r < 4; ++r) {
        int row = nb + q * 4 + r;
        if (row < N) {
            float s = dinv[row];
            o[(size_t)row * 64 + w * 16 + m] = (half_t)(acc2[r] * s);
        }
    }
}

// ---------------- gather2: 64-dim, eighth-wave per node, fp32 out -----------

__global__ void gather2_k(const half_t* __restrict__ hs,
                          const unsigned short* __restrict__ ssrc,
                          const int* __restrict__ rs,
                          const float* __restrict__ dinv,
                          const float* __restrict__ bias,
                          float* __restrict__ o, int N, int E) {
    int wid = (int)((blockIdx.x * blockDim.x + threadIdx.x) >> 6);
    int lane = threadIdx.x & 63;
    const int sg = lane >> 3, l3 = lane & 7;
    int rnode = wid * 8 + sg;                  // this eighth's node
    int node = (rnode < N) ? rnode : (N - 1);

    int start = rs[node];
    int end = (node + 1 < N) ? rs[node + 1] : E;
    float dv = dinv[node];
    const int sl = sg * 8;

    const half_t* hp = hs + 8 * l3;            // dims 8*l3 .. 8*l3+7
    f16x8 sv = *(const f16x8*)&hp[(size_t)node * 64];
    float acc[8];
#pragma unroll
    for (int j = 0; j < 8; ++j) acc[j] = (float)sv[j];   // self (pre-scaled)

    for (int base = start; base < end; base += 8) {
        int n = end - base;
        if (n > 8) n = 8;
        int gi = (base + l3 < end) ? (base + l3) : base;
        int idx = (int)ssrc[gi];
        int e = 0;
        for (; e + 4 <= n; e += 4) {           // 4 edges in flight per eighth
            int s0 = __shfl(idx, sl + e + 0);
            int s1 = __shfl(idx, sl + e + 1);
            int s2 = __shfl(idx, sl + e + 2);
            int s3 = __shfl(idx, sl + e + 3);
            f16x8 a0 = *(const f16x8*)&hp[(size_t)s0 * 64];
            f16x8 a1 = *(const f16x8*)&hp[(size_t)s1 * 64];
            f16x8 a2 = *(const f16x8*)&hp[(size_t)s2 * 64];
            f16x8 a3 = *(const f16x8*)&hp[(size_t)s3 * 64];
#pragma unroll
            for (int j = 0; j < 8; ++j) acc[j] += (float)a0[j];
#pragma unroll
            for (int j = 0; j < 8; ++j) acc[j] += (float)a1[j];
#pragma unroll
            for (int j = 0; j < 8; ++j) acc[j] += (float)a2[j];
#pragma unroll
            for (int j = 0; j < 8; ++j) acc[j] += (float)a3[j];
        }
        for (; e < n; ++e) {
            int s0 = __shfl(idx, sl + e);
            f16x8 a0 = *(const f16x8*)&hp[(size_t)s0 * 64];
#pragma unroll
            for (int j = 0; j < 8; ++j) acc[j] += (float)a0[j];
        }
    }
    if (rnode < N) {
        float4 b0 = *(const float4*)&bias[8 * l3];
        float4 b1v = *(const float4*)&bias[8 * l3 + 4];
        float4 o0, o1;
        o0.x = acc[0] * dv + b0.x;
        o0.y = acc[1] * dv + b0.y;
        o0.z = acc[2] * dv + b0.z;
        o0.w = acc[3] * dv + b0.w;
        o1.x = acc[4] * dv + b1v.x;
        o1.y = acc[5] * dv + b1v.y;
        o1.z = acc[6] * dv + b1v.z;
        o1.w = acc[7] * dv + b1v.w;
        *(float4*)&o[(size_t)rnode * 64 + 8 * l3] = o0;
        *(float4*)&o[(size_t)rnode * 64 + 8 * l3 + 4] = o1;
    }
}

// ---------------- launcher ----------------

extern "C" void kernel_launch(void* const* d_in, const int* in_sizes, int n_in,
                              void* d_out, int out_size, void* d_ws, size_t ws_size,
                              hipStream_t stream) {
    const float* x  = (const float*)d_in[0];
    const int*   ei = (const int*)d_in[1];
    const float* W1 = (const float*)d_in[2];
    const float* b1 = (const float*)d_in[3];
    const float* W2 = (const float*)d_in[4];
    const float* b2 = (const float*)d_in[5];
    float* out = (float*)d_out;

    const int N = in_sizes[0] / 128;
    const int E = in_sizes[1] / 2;
    const int* esrc = ei;
    const int* edst = ei + E;

    const int NB  = (N + 255) / 256;          // buckets (<=256 requires N<=65536)
    const int Gg1 = (N + 127) / 128;
    const int GA  = (E + 4095) / 4096;

    // workspace layout
    int* bucket_cnt = (int*)d_ws;                             // 256
    unsigned int* ebuf = (unsigned int*)(bucket_cnt + 256);   // NB*BKT_CAP packed edges
    unsigned short* ssrc = (unsigned short*)(ebuf + (size_t)NB * BKT_CAP); // E uint16
    int* rs = (int*)(ssrc + ((E + 1) & ~1));                  // N
    float* dinv = (float*)(rs + N);                           // N
    half_t* hs1 = (half_t*)(dinv + N);                        // 2 panels [N][64] fp16
    half_t* glo = hs1 + (size_t)N * 128;                      // N*64 fp16 (g1 dims 0-63)
    half_t* hs2 = glo + (size_t)N * 64;                       // N*64 fp16 (pre-scaled)

    hipMemsetAsync(bucket_cnt, 0, 256 * 4, stream);

    // k1: gemm1 (panel fp16 h1, unscaled) ∪ pass-A edge binning
    hipLaunchKernelGGL(gemm_binA_k, dim3(Gg1 + GA), dim3(256), 0, stream,
                       x, W1, hs1, N, Gg1, esrc, edst, bucket_cnt, ebuf, E);
    // k2: per-bucket counting sort (dst, src-tile) -> rs, dinv, ssrc
    hipLaunchKernelGGL(binB_k, dim3(NB), dim3(256), 0, stream,
                       bucket_cnt, ebuf, ssrc, rs, dinv, N, NB);
    // gather1 pass 0 (panel0, 6.4MB working set) -> g1_lo
    hipLaunchKernelGGL(g1a_k, dim3((N + 15) / 16), dim3(256), 0, stream,
                       hs1, ssrc, rs, dinv, b1, glo, N, E);
    // gather1 pass 1 (panel1) + gemm2 -> hs2 (pre-scaled)
    hipLaunchKernelGGL(g1b_k, dim3((N + 15) / 16), dim3(256), 0, stream,
                       hs1 + (size_t)N * 64, glo, ssrc, rs, dinv, b1, W2, hs2, N, E);
    // layer-2 aggregate
    hipLaunchKernelGGL(gather2_k, dim3((N + 31) / 32), dim3(256), 0, stream,
                       hs2, ssrc, rs, dinv, b2, out, N, E);
}